// Round 7
// baseline (584.164 us; speedup 1.0000x reference)
//
#include <hip/hip_runtime.h>
#include <stdint.h>

#define N_NODES 200000
#define NPL     12500
#define NLVL    16
#define DEG     8
#define EPL     (NPL*DEG)     // 100000
#define HD      128
#define KTOT    256           // concat K: [x | m]
#define MT      32            // rows per block (verified best on frag-major B)
#define NBLK    391           // ceil(12500/32)
#define PB      782           // pregather blocks per layer: ceil(12500/16)
#define ASTR    264           // A-tile row stride (bf16), +8 pad
#define WTL     98304         // Wt elems per layer: 192 tiles x 64 lanes x 8

typedef unsigned short u16;
typedef unsigned int   u32;

typedef __attribute__((ext_vector_type(8)))  short  short8;   // 8 bf16 = 4 VGPR (MFMA A/B frag)
typedef __attribute__((ext_vector_type(16))) float  f32x16;   // 32x32 MFMA C/D frag

__device__ __forceinline__ float bf2f(u32 u) { return __uint_as_float(u << 16); }
__device__ __forceinline__ float bflo(u32 u) { return __uint_as_float(u << 16); }
__device__ __forceinline__ float bfhi(u32 u) { return __uint_as_float(u & 0xFFFF0000u); }
__device__ __forceinline__ u16 f2bf(float f) {
  u32 u = __float_as_uint(f);
  return (u16)((u + 0x7FFFu + ((u >> 16) & 1u)) >> 16);   // RNE
}
__device__ __forceinline__ u32 pack2(float a, float b) {
  u32 ua = __float_as_uint(a), ub = __float_as_uint(b);
  ua = (ua + 0x7FFFu + ((ua >> 16) & 1u)) >> 16;
  ub = ((ub + 0x7FFFu + ((ub >> 16) & 1u)) >> 16) << 16;
  return ua | ub;
}
__device__ __forceinline__ float fsig(float x) {
  return __builtin_amdgcn_rcpf(1.f + __builtin_amdgcn_exp2f(-1.4426950408889634f * x));
}
__device__ __forceinline__ float ftanh(float x) {
  float t = __builtin_amdgcn_exp2f(2.8853900817779268f * x);   // e^(2x)
  return 1.f - 2.f * __builtin_amdgcn_rcpf(t + 1.f);           // inf-safe at both ends
}

// x init: x[index_map[i]] = bf16(features[i])
__global__ __launch_bounds__(256) void scatter_x(const float* __restrict__ f,
    const int* __restrict__ idx, u16* __restrict__ xb)
{
  const int t = blockIdx.x * 256 + threadIdx.x;   // 3.2M threads, 16 per row
  const int i = t >> 4, sg = (t & 15) * 8;
  const int d = idx[i];
  const float4 a = *(const float4*)(f + (size_t)i * HD + sg);
  const float4 b = *(const float4*)(f + (size_t)i * HD + sg + 4);
  uint4 o;
  o.x = pack2(a.x, a.y); o.y = pack2(a.z, a.w);
  o.z = pack2(b.x, b.y); o.w = pack2(b.z, b.w);
  *(uint4*)(xb + (size_t)d * HD + sg) = o;
}

// out[i] = fp32(h_final[index_map[i]])
__global__ __launch_bounds__(256) void gather_out(const u16* __restrict__ hb,
    const int* __restrict__ idx, float* __restrict__ o)
{
  const int t = blockIdx.x * 256 + threadIdx.x;
  const int i = t >> 4, sg = (t & 15) * 8;
  const int s = idx[i];
  const uint4 v = *(const uint4*)(hb + (size_t)s * HD + sg);
  float4 lo, hi;
  lo.x = bflo(v.x); lo.y = bfhi(v.x); lo.z = bflo(v.y); lo.w = bfhi(v.y);
  hi.x = bflo(v.z); hi.y = bfhi(v.z); hi.z = bflo(v.w); hi.w = bfhi(v.w);
  *(float4*)(o + (size_t)i * HD + sg)     = lo;
  *(float4*)(o + (size_t)i * HD + sg + 4) = hi;
}

// Fragment-major Wt: per layer, 192 tiles of (64 lanes x 8 k-elems) = 1 KB.
//   tiles [0,128):   RZ  (cols 0..255,  k 0..255):  tile = g*16 + t
//   tiles [128,160): GXN (cols 256..383, k 0..127): tile = 128 + g*8 + t
//   tiles [160,192): GHN (cols 384..511, k 128..255): tile = 160 + g*8 + (t-8)
// GXN k>=128 and GHN k<128 are structurally zero -> not stored, not multiplied.
__global__ __launch_bounds__(256) void build_wt(const float* __restrict__ wx,
    const float* __restrict__ wh, u16* __restrict__ wt)
{
  const int t = blockIdx.x * 256 + threadIdx.x;   // < 196608
  const int l = t / WTL;
  const int r = t - l * WTL;
  const int e = r & 7;
  const int chunk = r >> 3;
  const int lane = chunk & 63;
  const int tile = chunk >> 6;          // 0..191
  const int l31 = lane & 31, lq = lane >> 5;
  int col, k;
  if (tile < 128)      { col =       (tile >> 4) * 32 + l31; k =       (tile & 15) * 16 + lq * 8 + e; }
  else if (tile < 160) { col = 256 + ((tile - 128) >> 3) * 32 + l31; k = ((tile - 128) & 7) * 16 + lq * 8 + e; }
  else                 { col = 384 + ((tile - 160) >> 3) * 32 + l31; k = 128 + ((tile - 160) & 7) * 16 + lq * 8 + e; }
  float v;
  if (col < 384) {   // RZ full-K, GXN (k<128 by construction)
    v = (k < 128) ? wx[(size_t)(l * 128 + k) * 384 + col]
                  : wh[(size_t)l * 49152 + (size_t)(k - 128) * 384 + col];
  } else {           // GHN (k>=128 by construction)
    v = wh[(size_t)l * 49152 + (size_t)(k - 128) * 384 + (col - 128)];
  }
  wt[(size_t)l * WTL + r] = f2bf(v);
}

// Stage s with speculative pre-gather.
//   Blocks [0,NBLK):        main, layer-0 level s
//   Blocks [NBLK,2*NBLK):   main, layer-1 level s-1
//   Blocks [2*NBLK, +PB):   pregather for layer-0 level s+1 (src < s*NPL)
//   Blocks [.., +PB):       pregather for layer-1 level s   (src < (s-1)*NPL)
// Pregather sums edges whose src level is ALREADY FINAL before this stage
// (cutoff = (target_lvl-1)*NPL) into fp32 mAcc[gen=(s+1)&1] -- disjoint
// from rows main writes, so no race. Main at stage t reads mAcc[t&1] and
// fetches only deferred edges (src >= (lvl-1)*NPL, expected 8/lvl of 8).
// This moves ~(1 - 1/lvl) of the random gather off the serial critical
// path into blocks that run concurrently with the GEMM/epilogue.
__global__ __launch_bounds__(256, 4) void level_step_pg(
    u16* __restrict__ bufA, u16* __restrict__ bufB,
    const u16* __restrict__ wt, const float* __restrict__ bias,
    const int* __restrict__ esrc, float* __restrict__ mAcc, int stage)
{
  __shared__ __align__(16) u16 sA[MT * ASTR];     // 16,896 B
  const int tid = threadIdx.x;
  const int blk0 = blockIdx.x;

  if (blk0 >= 2 * NBLK) {
    // ---------------- pregather path ----------------
    const int pb   = blk0 - 2 * NBLK;
    const int L    = (pb < PB) ? 0 : 1;
    const int pblk = L ? (pb - PB) : pb;
    const int tlvl = L ? stage : stage + 1;        // target level
    if (tlvl < 1 || tlvl >= NLVL) return;
    const int row = pblk * 16 + (tid >> 4);
    if (row >= NPL) return;
    const int c8 = (tid & 15) * 8;
    const int cutoff = (tlvl - 1) * NPL;
    const u16* hs = L ? bufA : bufB;               // h1 : h0
    const int eb = (tlvl - 1) * EPL + row * DEG;
    const int4 e0 = *(const int4*)(esrc + eb);
    const int4 e1 = *(const int4*)(esrc + eb + 4);
    const int srcs[8] = { e0.x, e0.y, e0.z, e0.w, e1.x, e1.y, e1.z, e1.w };
    float acc[8];
    #pragma unroll
    for (int i = 0; i < 8; ++i) acc[i] = 0.f;
    #pragma unroll
    for (int e = 0; e < 8; ++e) {
      if (srcs[e] < cutoff) {                      // finalized rows only
        const uint4 v = *(const uint4*)(hs + (size_t)srcs[e] * HD + c8);
        acc[0] += bflo(v.x); acc[1] += bfhi(v.x);
        acc[2] += bflo(v.y); acc[3] += bfhi(v.y);
        acc[4] += bflo(v.z); acc[5] += bfhi(v.z);
        acc[6] += bflo(v.w); acc[7] += bfhi(v.w);
      }
    }
    float* mp = mAcc + ((size_t)((((stage + 1) & 1) * 2) + L) * NPL + row) * HD + c8;
    float4 o0, o1;
    o0.x = acc[0]; o0.y = acc[1]; o0.z = acc[2]; o0.w = acc[3];
    o1.x = acc[4]; o1.y = acc[5]; o1.z = acc[6]; o1.w = acc[7];
    *(float4*)(mp)     = o0;
    *(float4*)(mp + 4) = o1;
    return;
  }

  // ---------------- main path ----------------
  int blk = blk0, layer, lvl;
  if (blk < NBLK) { layer = 0; lvl = stage; }
  else            { layer = 1; lvl = stage - 1; blk -= NBLK; }
  if (lvl < 0 || lvl >= NLVL) return;

  const u16*   x  = layer ? bufB : bufA;          // L0: scattered x; L1: h0
  u16*         h  = layer ? bufA : bufB;          // L0: h0; L1: h1 (final)
  const u16*   Wt = wt  + (size_t)layer * WTL;
  const float* bs = bias + (size_t)layer * 384;

  // ---- stage A-tile: x part (k 0..127) and m part (k 128..255) ----
  {
    const int sub = tid >> 4;          // 0..15: row within a 16-row group
    const int c8  = (tid & 15) * 8;    // element offset, 16 B per thread
    uint4 z4; z4.x = z4.y = z4.z = z4.w = 0u;
    #pragma unroll
    for (int it = 0; it < 2; ++it) {
      const int row  = it * 16 + sub;
      const int lrow = blk * MT + row;
      const bool valid = (lrow < NPL);
      uint4* dx = (uint4*)(sA + row * ASTR + c8);
      *dx = valid ? *(const uint4*)(x + (size_t)(lvl * NPL + lrow) * HD + c8) : z4;
      uint4* dm = (uint4*)(sA + row * ASTR + HD + c8);
      if (lvl > 0 && valid) {
        const int cutoff = (lvl - 1) * NPL;
        const float* mp = mAcc + ((size_t)(((stage & 1) * 2) + layer) * NPL + lrow) * HD + c8;
        const float4 p0 = *(const float4*)(mp);
        const float4 p1 = *(const float4*)(mp + 4);
        float acc[8];
        acc[0] = p0.x; acc[1] = p0.y; acc[2] = p0.z; acc[3] = p0.w;
        acc[4] = p1.x; acc[5] = p1.y; acc[6] = p1.z; acc[7] = p1.w;
        const int eb = (lvl - 1) * EPL + lrow * DEG;
        const int4 e0 = *(const int4*)(esrc + eb);
        const int4 e1 = *(const int4*)(esrc + eb + 4);
        const int srcs[8] = { e0.x, e0.y, e0.z, e0.w, e1.x, e1.y, e1.z, e1.w };
        #pragma unroll
        for (int e = 0; e < 8; ++e) {
          if (srcs[e] >= cutoff) {                 // deferred (newest-level) edges
            const uint4 v = *(const uint4*)(h + (size_t)srcs[e] * HD + c8);
            acc[0] += bflo(v.x); acc[1] += bfhi(v.x);
            acc[2] += bflo(v.y); acc[3] += bfhi(v.y);
            acc[4] += bflo(v.z); acc[5] += bfhi(v.z);
            acc[6] += bflo(v.w); acc[7] += bfhi(v.w);
          }
        }
        uint4 o;
        o.x = pack2(acc[0] * 0.125f, acc[1] * 0.125f);
        o.y = pack2(acc[2] * 0.125f, acc[3] * 0.125f);
        o.z = pack2(acc[4] * 0.125f, acc[5] * 0.125f);
        o.w = pack2(acc[6] * 0.125f, acc[7] * 0.125f);
        *dm = o;
      } else {
        *dm = z4;   // level 0: m = 0
      }
    }
  }
  __syncthreads();   // the only barrier: K-loop below is barrier-free

  const int wv = tid >> 6, lane = tid & 63;
  const int l31 = lane & 31, lq = lane >> 5;

  // acc[gate-group]; fp32 bias folded into init (gh_n group gets 0)
  f32x16 acc[4];
  {
    const float b0 = bs[      32 * wv + l31];
    const float b1 = bs[128 + 32 * wv + l31];
    const float b2 = bs[256 + 32 * wv + l31];
    #pragma unroll
    for (int r = 0; r < 16; ++r) {
      acc[0][r] = b0; acc[1][r] = b1; acc[2][r] = b2; acc[3][r] = 0.f;
    }
  }

  // ---- K loop over 16 k-steps: A from LDS, B fragment-major from global ----
  const u16* wlane = Wt + (size_t)lane * 8;
  #pragma unroll
  for (int t = 0; t < 16; ++t) {
    const short8 a0  = *(const short8*)(sA + l31 * ASTR + t * 16 + lq * 8);
    const short8 bb0 = *(const short8*)(wlane + (size_t)((wv    ) * 16 + t) * 512);
    const short8 bb1 = *(const short8*)(wlane + (size_t)((wv + 4) * 16 + t) * 512);
    acc[0] = __builtin_amdgcn_mfma_f32_32x32x16_bf16(a0, bb0, acc[0], 0, 0, 0);
    acc[1] = __builtin_amdgcn_mfma_f32_32x32x16_bf16(a0, bb1, acc[1], 0, 0, 0);
    if (t < 8) {
      const short8 bb2 = *(const short8*)(wlane + (size_t)(128 + wv * 8 + t) * 512);
      acc[2] = __builtin_amdgcn_mfma_f32_32x32x16_bf16(a0, bb2, acc[2], 0, 0, 0);
    } else {
      const short8 bb3 = *(const short8*)(wlane + (size_t)(160 + wv * 8 + (t - 8)) * 512);
      acc[3] = __builtin_amdgcn_mfma_f32_32x32x16_bf16(a0, bb3, acc[3], 0, 0, 0);
    }
  }

  // ---- epilogue: r,z,n gates in-register; m from A-tile; bf16 store ----
  const int jcol = 32 * wv + l31;
  #pragma unroll
  for (int r = 0; r < 16; ++r) {
    const int rowe = (r & 3) + 8 * (r >> 2) + 4 * lq;  // C-layout row, 0..31
    const int lrow = blk * MT + rowe;
    if (lrow < NPL) {
      const float gr  = acc[0][r];
      const float gz  = acc[1][r];
      const float gxn = acc[2][r];
      const float ghn = acc[3][r];
      const float mv  = bf2f(sA[rowe * ASTR + HD + jcol]);
      const float rg  = fsig(gr);
      const float zg  = fsig(gz);
      const float ng  = ftanh(gxn + rg * ghn);
      const float hv  = (1.f - zg) * ng + zg * mv;
      h[(size_t)(lvl * NPL + lrow) * HD + jcol] = f2bf(hv);
    }
  }
}

// Fallback (verified R6, 538.6us): used when ws_size can't hold mAcc.
__global__ __launch_bounds__(256, 4) void level_step(
    u16* __restrict__ bufA, u16* __restrict__ bufB,
    const u16* __restrict__ wt, const float* __restrict__ bias,
    const int* __restrict__ esrc, int stage)
{
  __shared__ __align__(16) u16 sA[MT * ASTR];     // 16,896 B

  int blk = blockIdx.x, layer, lvl;
  if (blk < NBLK) { layer = 0; lvl = stage; }
  else            { layer = 1; lvl = stage - 1; blk -= NBLK; }
  if (lvl < 0 || lvl >= NLVL) return;

  const u16*   x  = layer ? bufB : bufA;
  u16*         h  = layer ? bufA : bufB;
  const u16*   Wt = wt  + (size_t)layer * WTL;
  const float* bs = bias + (size_t)layer * 384;

  const int tid = threadIdx.x;
  {
    const int sub = tid >> 4;
    const int c8  = (tid & 15) * 8;
    uint4 z4; z4.x = z4.y = z4.z = z4.w = 0u;
    #pragma unroll
    for (int it = 0; it < 2; ++it) {
      const int row  = it * 16 + sub;
      const int lrow = blk * MT + row;
      const bool valid = (lrow < NPL);
      uint4* dx = (uint4*)(sA + row * ASTR + c8);
      *dx = valid ? *(const uint4*)(x + (size_t)(lvl * NPL + lrow) * HD + c8) : z4;
      uint4* dm = (uint4*)(sA + row * ASTR + HD + c8);
      if (lvl > 0 && valid) {
        const int eb = (lvl - 1) * EPL + lrow * DEG;
        const int4 e0 = *(const int4*)(esrc + eb);
        const int4 e1 = *(const int4*)(esrc + eb + 4);
        const int srcs[8] = { e0.x, e0.y, e0.z, e0.w, e1.x, e1.y, e1.z, e1.w };
        float acc[8];
        #pragma unroll
        for (int i = 0; i < 8; ++i) acc[i] = 0.f;
        #pragma unroll
        for (int e = 0; e < 8; ++e) {
          const uint4 v = *(const uint4*)(h + (size_t)srcs[e] * HD + c8);
          acc[0] += bflo(v.x); acc[1] += bfhi(v.x);
          acc[2] += bflo(v.y); acc[3] += bfhi(v.y);
          acc[4] += bflo(v.z); acc[5] += bfhi(v.z);
          acc[6] += bflo(v.w); acc[7] += bfhi(v.w);
        }
        uint4 o;
        o.x = pack2(acc[0] * 0.125f, acc[1] * 0.125f);
        o.y = pack2(acc[2] * 0.125f, acc[3] * 0.125f);
        o.z = pack2(acc[4] * 0.125f, acc[5] * 0.125f);
        o.w = pack2(acc[6] * 0.125f, acc[7] * 0.125f);
        *dm = o;
      } else {
        *dm = z4;
      }
    }
  }
  __syncthreads();

  const int wv = tid >> 6, lane = tid & 63;
  const int l31 = lane & 31, lq = lane >> 5;

  f32x16 acc[4];
  {
    const float b0 = bs[      32 * wv + l31];
    const float b1 = bs[128 + 32 * wv + l31];
    const float b2 = bs[256 + 32 * wv + l31];
    #pragma unroll
    for (int r = 0; r < 16; ++r) {
      acc[0][r] = b0; acc[1][r] = b1; acc[2][r] = b2; acc[3][r] = 0.f;
    }
  }

  const u16* wlane = Wt + (size_t)lane * 8;
  #pragma unroll
  for (int t = 0; t < 16; ++t) {
    const short8 a0  = *(const short8*)(sA + l31 * ASTR + t * 16 + lq * 8);
    const short8 bb0 = *(const short8*)(wlane + (size_t)((wv    ) * 16 + t) * 512);
    const short8 bb1 = *(const short8*)(wlane + (size_t)((wv + 4) * 16 + t) * 512);
    acc[0] = __builtin_amdgcn_mfma_f32_32x32x16_bf16(a0, bb0, acc[0], 0, 0, 0);
    acc[1] = __builtin_amdgcn_mfma_f32_32x32x16_bf16(a0, bb1, acc[1], 0, 0, 0);
    if (t < 8) {
      const short8 bb2 = *(const short8*)(wlane + (size_t)(128 + wv * 8 + t) * 512);
      acc[2] = __builtin_amdgcn_mfma_f32_32x32x16_bf16(a0, bb2, acc[2], 0, 0, 0);
    } else {
      const short8 bb3 = *(const short8*)(wlane + (size_t)(160 + wv * 8 + (t - 8)) * 512);
      acc[3] = __builtin_amdgcn_mfma_f32_32x32x16_bf16(a0, bb3, acc[3], 0, 0, 0);
    }
  }

  const int jcol = 32 * wv + l31;
  #pragma unroll
  for (int r = 0; r < 16; ++r) {
    const int rowe = (r & 3) + 8 * (r >> 2) + 4 * lq;
    const int lrow = blk * MT + rowe;
    if (lrow < NPL) {
      const float gr  = acc[0][r];
      const float gz  = acc[1][r];
      const float gxn = acc[2][r];
      const float ghn = acc[3][r];
      const float mv  = bf2f(sA[rowe * ASTR + HD + jcol]);
      const float rg  = fsig(gr);
      const float zg  = fsig(gz);
      const float ng  = ftanh(gxn + rg * ghn);
      const float hv  = (1.f - zg) * ng + zg * mv;
      h[(size_t)(lvl * NPL + lrow) * HD + jcol] = f2bf(hv);
    }
  }
}

extern "C" void kernel_launch(void* const* d_in, const int* in_sizes, int n_in,
                              void* d_out, int out_size, void* d_ws, size_t ws_size,
                              hipStream_t stream)
{
  (void)in_sizes; (void)n_in; (void)out_size;
  const float* feats = (const float*)d_in[0];
  const float* wx    = (const float*)d_in[1];
  const float* wh    = (const float*)d_in[2];
  const float* bias  = (const float*)d_in[3];
  const int*   esrc  = (const int*)d_in[4];
  const int*   imap  = (const int*)d_in[6];
  float* out = (float*)d_out;

  char* ws = (char*)d_ws;
  u16* bufA = (u16*)ws;                       // 51,200,000 B  (x, then h1)
  u16* bufB = (u16*)(ws + 51200000);          // 51,200,000 B  (h0)
  u16* wt   = (u16*)(ws + 102400000);         // 393,216 B  (2 x 192-tile frag-major)
  const size_t MACC_OFF = 102793216;          // 16B-aligned
  const size_t WS_NEED  = MACC_OFF + 2ull * 2ull * NPL * HD * 4ull;  // +25.6 MB

  scatter_x<<<12500, 256, 0, stream>>>(feats, imap, bufA);
  build_wt<<<768, 256, 0, stream>>>(wx, wh, wt);

  if (ws_size >= WS_NEED) {
    float* mAcc = (float*)(ws + MACC_OFF);    // [gen][layer][NPL][HD] fp32
    for (int stage = 0; stage <= NLVL; ++stage)
      level_step_pg<<<2 * NBLK + 2 * PB, 256, 0, stream>>>(
          bufA, bufB, wt, bias, esrc, mAcc, stage);
  } else {
    for (int stage = 0; stage <= NLVL; ++stage)
      level_step<<<2 * NBLK, 256, 0, stream>>>(bufA, bufB, wt, bias, esrc, stage);
  }

  gather_out<<<12500, 256, 0, stream>>>(bufA, imap, out);
}

// Round 8
// 531.847 us; speedup vs baseline: 1.0984x; 1.0984x over previous
//
#include <hip/hip_runtime.h>
#include <stdint.h>

#define N_NODES 200000
#define NPL     12500
#define NLVL    16
#define DEG     8
#define EPL     (NPL*DEG)     // 100000
#define HD      128
#define KTOT    256           // concat K: [x | m]
#define MT      32            // rows per block (verified best on frag-major B)
#define NBLK    391           // ceil(12500/32)
#define ASTR    264           // A-tile row stride (bf16), +8 pad
#define WTL     98304         // Wt elems per layer: 192 tiles x 64 lanes x 8
#define GOBLK   12500         // gather-out blocks (200000 rows x 16 thr/row)

typedef unsigned short u16;
typedef unsigned int   u32;

typedef __attribute__((ext_vector_type(8)))  short  short8;   // 8 bf16 = 4 VGPR (MFMA A/B frag)
typedef __attribute__((ext_vector_type(16))) float  f32x16;   // 32x32 MFMA C/D frag

__device__ __forceinline__ float bf2f(u32 u) { return __uint_as_float(u << 16); }
__device__ __forceinline__ float bflo(u32 u) { return __uint_as_float(u << 16); }
__device__ __forceinline__ float bfhi(u32 u) { return __uint_as_float(u & 0xFFFF0000u); }
__device__ __forceinline__ u16 f2bf(float f) {
  u32 u = __float_as_uint(f);
  return (u16)((u + 0x7FFFu + ((u >> 16) & 1u)) >> 16);   // RNE
}
__device__ __forceinline__ u32 pack2(float a, float b) {
  u32 ua = __float_as_uint(a), ub = __float_as_uint(b);
  ua = (ua + 0x7FFFu + ((ua >> 16) & 1u)) >> 16;
  ub = ((ub + 0x7FFFu + ((ub >> 16) & 1u)) >> 16) << 16;
  return ua | ub;
}
__device__ __forceinline__ float fsig(float x) {
  return __builtin_amdgcn_rcpf(1.f + __builtin_amdgcn_exp2f(-1.4426950408889634f * x));
}
__device__ __forceinline__ float ftanh(float x) {
  float t = __builtin_amdgcn_exp2f(2.8853900817779268f * x);   // e^(2x)
  return 1.f - 2.f * __builtin_amdgcn_rcpf(t + 1.f);           // inf-safe at both ends
}

// Fused: blocks [0,12500) scatter x; blocks [12500,13268) build frag-major Wt.
// Saves one launch boundary; the 768 build blocks ride in scatter's BW shadow.
__global__ __launch_bounds__(256) void scatter_build(
    const float* __restrict__ f, const int* __restrict__ idx, u16* __restrict__ xb,
    const float* __restrict__ wx, const float* __restrict__ wh, u16* __restrict__ wt)
{
  if (blockIdx.x < GOBLK) {
    // x init: x[index_map[i]] = bf16(features[i])
    const int t = blockIdx.x * 256 + threadIdx.x;   // 3.2M threads, 16 per row
    const int i = t >> 4, sg = (t & 15) * 8;
    const int d = idx[i];
    const float4 a = *(const float4*)(f + (size_t)i * HD + sg);
    const float4 b = *(const float4*)(f + (size_t)i * HD + sg + 4);
    uint4 o;
    o.x = pack2(a.x, a.y); o.y = pack2(a.z, a.w);
    o.z = pack2(b.x, b.y); o.w = pack2(b.z, b.w);
    *(uint4*)(xb + (size_t)d * HD + sg) = o;
    return;
  }
  // Fragment-major Wt: per layer, 192 tiles of (64 lanes x 8 k-elems) = 1 KB.
  //   tiles [0,128):   RZ  (cols 0..255,  k 0..255):  tile = g*16 + t
  //   tiles [128,160): GXN (cols 256..383, k 0..127): tile = 128 + g*8 + t
  //   tiles [160,192): GHN (cols 384..511, k 128..255): tile = 160 + g*8 + (t-8)
  // GXN k>=128 and GHN k<128 are structurally zero -> not stored, not multiplied.
  const int t = (blockIdx.x - GOBLK) * 256 + threadIdx.x;   // < 196608
  const int l = t / WTL;
  const int r = t - l * WTL;
  const int e = r & 7;
  const int chunk = r >> 3;
  const int lane = chunk & 63;
  const int tile = chunk >> 6;          // 0..191
  const int l31 = lane & 31, lq = lane >> 5;
  int col, k;
  if (tile < 128)      { col =       (tile >> 4) * 32 + l31; k =       (tile & 15) * 16 + lq * 8 + e; }
  else if (tile < 160) { col = 256 + ((tile - 128) >> 3) * 32 + l31; k = ((tile - 128) & 7) * 16 + lq * 8 + e; }
  else                 { col = 384 + ((tile - 160) >> 3) * 32 + l31; k = 128 + ((tile - 160) & 7) * 16 + lq * 8 + e; }
  float v;
  if (col < 384) {   // RZ full-K, GXN (k<128 by construction)
    v = (k < 128) ? wx[(size_t)(l * 128 + k) * 384 + col]
                  : wh[(size_t)l * 49152 + (size_t)(k - 128) * 384 + col];
  } else {           // GHN (k>=128 by construction)
    v = wh[(size_t)l * 49152 + (size_t)(k - 128) * 384 + (col - 128)];
  }
  wt[(size_t)l * WTL + r] = f2bf(v);
}

// Tail of the output gather: rows whose h1 source is in level 15 (written by
// the stage-16 launch). ~1/16 of rows do the copy; the rest exit after the
// idx read. Runs after the last stage.
__global__ __launch_bounds__(256) void gather_tail(const u16* __restrict__ hb,
    const int* __restrict__ idx, float* __restrict__ o)
{
  const int t = blockIdx.x * 256 + threadIdx.x;
  const int i = t >> 4, sg = (t & 15) * 8;
  const int s = idx[i];
  if (s < (NLVL - 1) * NPL) return;     // already written inside stage 16
  const uint4 v = *(const uint4*)(hb + (size_t)s * HD + sg);
  float4 lo, hi;
  lo.x = bflo(v.x); lo.y = bfhi(v.x); lo.z = bflo(v.y); lo.w = bfhi(v.y);
  hi.x = bflo(v.z); hi.y = bfhi(v.z); hi.z = bflo(v.w); hi.w = bfhi(v.w);
  *(float4*)(o + (size_t)i * HD + sg)     = lo;
  *(float4*)(o + (size_t)i * HD + sg + 4) = hi;
}

// Stage s: blocks [0,NBLK) layer-0 level s; [NBLK,2*NBLK) layer-1 level s-1.
// Body identical to the verified 538.6us R6 kernel. At stage==NLVL only,
// extra blocks [2*NBLK, 2*NBLK+GOBLK) perform the bulk output gather for
// rows with source level < 15 (final after stage 15 -> disjoint from the
// level-15 rows the main blocks write). This uses the stage-16 launch's
// idle capacity (its layer-0 half exits immediately) and removes most of
// the separate gather_out kernel from the serial chain.
__global__ __launch_bounds__(256, 4) void level_step(
    u16* __restrict__ bufA, u16* __restrict__ bufB,
    const u16* __restrict__ wt, const float* __restrict__ bias,
    const int* __restrict__ esrc, const int* __restrict__ imap,
    float* __restrict__ out, int stage)
{
  __shared__ __align__(16) u16 sA[MT * ASTR];     // 16,896 B

  const int blk0 = blockIdx.x;
  const int tid  = threadIdx.x;

  if (blk0 >= 2 * NBLK) {
    // ---- fused bulk gather_out (launched only at stage == NLVL) ----
    const int t = (blk0 - 2 * NBLK) * 256 + tid;
    const int i = t >> 4, sg = (t & 15) * 8;
    const int s = imap[i];
    if (s < (NLVL - 1) * NPL) {         // h1 levels 0..14: final after stage 15
      const uint4 v = *(const uint4*)(bufA + (size_t)s * HD + sg);
      float4 lo, hi;
      lo.x = bflo(v.x); lo.y = bfhi(v.x); lo.z = bflo(v.y); lo.w = bfhi(v.y);
      hi.x = bflo(v.z); hi.y = bfhi(v.z); hi.z = bflo(v.w); hi.w = bfhi(v.w);
      *(float4*)(out + (size_t)i * HD + sg)     = lo;
      *(float4*)(out + (size_t)i * HD + sg + 4) = hi;
    }
    return;
  }

  int blk = blk0, layer, lvl;
  if (blk < NBLK) { layer = 0; lvl = stage; }
  else            { layer = 1; lvl = stage - 1; blk -= NBLK; }
  if (lvl < 0 || lvl >= NLVL) return;

  const u16*   x  = layer ? bufB : bufA;          // L0: scattered x; L1: h0
  u16*         h  = layer ? bufA : bufB;          // L0: h0; L1: h1 (final)
  const u16*   Wt = wt  + (size_t)layer * WTL;
  const float* bs = bias + (size_t)layer * 384;

  // ---- stage A-tile: x part (k 0..127) and m part (k 128..255) ----
  {
    const int sub = tid >> 4;          // 0..15: row within a 16-row group
    const int c8  = (tid & 15) * 8;    // element offset, 16 B per thread
    uint4 z4; z4.x = z4.y = z4.z = z4.w = 0u;
    #pragma unroll
    for (int it = 0; it < 2; ++it) {
      const int row  = it * 16 + sub;
      const int lrow = blk * MT + row;
      const bool valid = (lrow < NPL);
      uint4* dx = (uint4*)(sA + row * ASTR + c8);
      *dx = valid ? *(const uint4*)(x + (size_t)(lvl * NPL + lrow) * HD + c8) : z4;
      uint4* dm = (uint4*)(sA + row * ASTR + HD + c8);
      if (lvl > 0 && valid) {
        const int eb = (lvl - 1) * EPL + lrow * DEG;
        const int4 e0 = *(const int4*)(esrc + eb);
        const int4 e1 = *(const int4*)(esrc + eb + 4);
        const int srcs[8] = { e0.x, e0.y, e0.z, e0.w, e1.x, e1.y, e1.z, e1.w };
        float acc[8];
        #pragma unroll
        for (int i = 0; i < 8; ++i) acc[i] = 0.f;
        #pragma unroll
        for (int e = 0; e < 8; ++e) {
          const uint4 v = *(const uint4*)(h + (size_t)srcs[e] * HD + c8);
          acc[0] += bflo(v.x); acc[1] += bfhi(v.x);
          acc[2] += bflo(v.y); acc[3] += bfhi(v.y);
          acc[4] += bflo(v.z); acc[5] += bfhi(v.z);
          acc[6] += bflo(v.w); acc[7] += bfhi(v.w);
        }
        uint4 o;
        o.x = pack2(acc[0] * 0.125f, acc[1] * 0.125f);
        o.y = pack2(acc[2] * 0.125f, acc[3] * 0.125f);
        o.z = pack2(acc[4] * 0.125f, acc[5] * 0.125f);
        o.w = pack2(acc[6] * 0.125f, acc[7] * 0.125f);
        *dm = o;
      } else {
        *dm = z4;   // level 0: m = 0
      }
    }
  }
  __syncthreads();   // the only barrier: K-loop below is barrier-free

  const int wv = tid >> 6, lane = tid & 63;
  const int l31 = lane & 31, lq = lane >> 5;

  // acc[gate-group]; fp32 bias folded into init (gh_n group gets 0)
  f32x16 acc[4];
  {
    const float b0 = bs[      32 * wv + l31];
    const float b1 = bs[128 + 32 * wv + l31];
    const float b2 = bs[256 + 32 * wv + l31];
    #pragma unroll
    for (int r = 0; r < 16; ++r) {
      acc[0][r] = b0; acc[1][r] = b1; acc[2][r] = b2; acc[3][r] = 0.f;
    }
  }

  // ---- K loop over 16 k-steps: A from LDS, B fragment-major from global ----
  const u16* wlane = Wt + (size_t)lane * 8;
  #pragma unroll
  for (int t = 0; t < 16; ++t) {
    const short8 a0  = *(const short8*)(sA + l31 * ASTR + t * 16 + lq * 8);
    const short8 bb0 = *(const short8*)(wlane + (size_t)((wv    ) * 16 + t) * 512);
    const short8 bb1 = *(const short8*)(wlane + (size_t)((wv + 4) * 16 + t) * 512);
    acc[0] = __builtin_amdgcn_mfma_f32_32x32x16_bf16(a0, bb0, acc[0], 0, 0, 0);
    acc[1] = __builtin_amdgcn_mfma_f32_32x32x16_bf16(a0, bb1, acc[1], 0, 0, 0);
    if (t < 8) {
      const short8 bb2 = *(const short8*)(wlane + (size_t)(128 + wv * 8 + t) * 512);
      acc[2] = __builtin_amdgcn_mfma_f32_32x32x16_bf16(a0, bb2, acc[2], 0, 0, 0);
    } else {
      const short8 bb3 = *(const short8*)(wlane + (size_t)(160 + wv * 8 + (t - 8)) * 512);
      acc[3] = __builtin_amdgcn_mfma_f32_32x32x16_bf16(a0, bb3, acc[3], 0, 0, 0);
    }
  }

  // ---- epilogue: r,z,n gates in-register; m from A-tile; bf16 store ----
  const int jcol = 32 * wv + l31;
  #pragma unroll
  for (int r = 0; r < 16; ++r) {
    const int rowe = (r & 3) + 8 * (r >> 2) + 4 * lq;  // C-layout row, 0..31
    const int lrow = blk * MT + rowe;
    if (lrow < NPL) {
      const float gr  = acc[0][r];
      const float gz  = acc[1][r];
      const float gxn = acc[2][r];
      const float ghn = acc[3][r];
      const float mv  = bf2f(sA[rowe * ASTR + HD + jcol]);
      const float rg  = fsig(gr);
      const float zg  = fsig(gz);
      const float ng  = ftanh(gxn + rg * ghn);
      const float hv  = (1.f - zg) * ng + zg * mv;
      h[(size_t)(lvl * NPL + lrow) * HD + jcol] = f2bf(hv);
    }
  }
}

extern "C" void kernel_launch(void* const* d_in, const int* in_sizes, int n_in,
                              void* d_out, int out_size, void* d_ws, size_t ws_size,
                              hipStream_t stream)
{
  (void)in_sizes; (void)n_in; (void)out_size; (void)ws_size;
  const float* feats = (const float*)d_in[0];
  const float* wx    = (const float*)d_in[1];
  const float* wh    = (const float*)d_in[2];
  const float* bias  = (const float*)d_in[3];
  const int*   esrc  = (const int*)d_in[4];
  const int*   imap  = (const int*)d_in[6];
  float* out = (float*)d_out;

  char* ws = (char*)d_ws;
  u16* bufA = (u16*)ws;                       // 51,200,000 B  (x, then h1)
  u16* bufB = (u16*)(ws + 51200000);          // 51,200,000 B  (h0)
  u16* wt   = (u16*)(ws + 102400000);         // 393,216 B  (2 x 192-tile frag-major)

  scatter_build<<<GOBLK + 768, 256, 0, stream>>>(feats, imap, bufA, wx, wh, wt);

  for (int stage = 0; stage < NLVL; ++stage)
    level_step<<<2 * NBLK, 256, 0, stream>>>(bufA, bufB, wt, bias, esrc,
                                             imap, out, stage);
  // stage 16: layer-1 level 15 + bulk output gather in the idle capacity
  level_step<<<2 * NBLK + GOBLK, 256, 0, stream>>>(bufA, bufB, wt, bias, esrc,
                                                   imap, out, NLVL);

  gather_tail<<<GOBLK, 256, 0, stream>>>(bufA, imap, out);
}